// Round 16
// baseline (255.690 us; speedup 1.0000x reference)
//
#include <hip/hip_runtime.h>
#include <hip/hip_fp16.h>

#define FEAT 64
#define HID 10
#define RS 16    // fp32 row stride (floats) -> 64B rows
#define BRS 4    // packed-fp12 B row stride (dwords) -> 16B rows
#define EPB 1024 // edges per block in binning passes -> ~1221 blocks
#define BSH 6    // bucket shift: 64 nodes per bucket
#define CHK 32   // block-rows per chunk in column-prefix passes

typedef __attribute__((ext_vector_type(2))) float f32x2;

#if defined(__has_builtin)
#if __has_builtin(__builtin_elementwise_fma)
#define HAVE_EW_FMA 1
#endif
#endif

__device__ __forceinline__ f32x2 pk_fma(f32x2 a, f32x2 b, f32x2 c) {
#ifdef HAVE_EW_FMA
    return __builtin_elementwise_fma(a, b, c);
#else
    f32x2 r; r.x = fmaf(a.x, b.x, c.x); r.y = fmaf(a.y, b.y, c.y); return r;
#endif
}
__device__ __forceinline__ f32x2 pk_max0(f32x2 a) {
    f32x2 r; r.x = fmaxf(a.x, 0.f); r.y = fmaxf(a.y, 0.f); return r;
}

// ---- fp12 (s1e5m6 = top 12 bits of fp16, RTN) codec ----
__device__ __forceinline__ unsigned int f2fp12(float v) {
    unsigned short h = __half_as_ushort(__float2half(v));
    return (((unsigned int)h) + 8u) >> 4;
}
__device__ __forceinline__ float fp12f(unsigned int f) {
    return __half2float(__ushort_as_half((unsigned short)(f << 4)));
}
__device__ __forceinline__ uint4 pack10(const float* b) {
    unsigned int f[10];
#pragma unroll
    for (int i = 0; i < 10; i++) f[i] = f2fp12(b[i]);
    uint4 d;
    d.x = f[0] | (f[1] << 12) | (f[2] << 24);
    d.y = (f[2] >> 8) | (f[3] << 4) | (f[4] << 16) | (f[5] << 28);
    d.z = (f[5] >> 4) | (f[6] << 8) | (f[7] << 20);
    d.w = f[8] | (f[9] << 12);
    return d;
}

// ---------- Layer-0 precompute: A=X@W2[0:64,:] (fp32), B=X@W2[64:128,:] (fp12 packed) ----------
__global__ __launch_bounds__(256) void pre_l0(
    const float* __restrict__ X,    // [NN,64]
    const float* __restrict__ W2,   // [128,10]
    float* __restrict__ A,          // [NN,RS] fp32
    unsigned int* __restrict__ Bt,  // [NN,BRS] packed fp12
    int n_nodes)
{
    __shared__ float w2[128 * 10];
    for (int i = threadIdx.x; i < 1280; i += 256) w2[i] = W2[i];
    __syncthreads();

    int n = blockIdx.x * 256 + threadIdx.x;
    if (n >= n_nodes) return;

    const float4* xr = reinterpret_cast<const float4*>(X + (size_t)n * FEAT);
    float a[10], b[10];
#pragma unroll
    for (int h = 0; h < 10; h++) { a[h] = 0.f; b[h] = 0.f; }

#pragma unroll
    for (int blk = 0; blk < 16; blk++) {
        float4 u = xr[blk];
        float xv[4] = { u.x, u.y, u.z, u.w };
#pragma unroll
        for (int j = 0; j < 4; j++) {
            int k = blk * 4 + j;
#pragma unroll
            for (int h = 0; h < 10; h++) {
                a[h] = fmaf(xv[j], w2[k * 10 + h], a[h]);
                b[h] = fmaf(xv[j], w2[(64 + k) * 10 + h], b[h]);
            }
        }
    }

    float4* Ar = reinterpret_cast<float4*>(A + (size_t)n * RS);
    Ar[0] = make_float4(a[0], a[1], a[2], a[3]);
    Ar[1] = make_float4(a[4], a[5], a[6], a[7]);
    Ar[2] = make_float4(a[8], a[9], 0.f, 0.f);
    *reinterpret_cast<uint4*>(Bt + (size_t)n * BRS) = pack10(b);
}

// ================= CSR build (R11-proven): two-level counting sort, LDS cursors only ==========

__global__ __launch_bounds__(256) void bin_hist_k(
    const int* __restrict__ dst, int* __restrict__ blockhist, int n_edges, int nbk)
{
    extern __shared__ int hist[];
    for (int i = threadIdx.x; i < nbk; i += 256) hist[i] = 0;
    __syncthreads();
    int base = blockIdx.x * EPB;
    for (int i = threadIdx.x; i < EPB; i += 256) {
        int e = base + i;
        if (e < n_edges) atomicAdd(&hist[dst[e] >> BSH], 1);
    }
    __syncthreads();
    int* row = blockhist + (size_t)blockIdx.x * nbk;
    for (int i = threadIdx.x; i < nbk; i += 256) row[i] = hist[i];
}

// chunksum is stored TRANSPOSED: chunksum[b * nchk + c]
__global__ __launch_bounds__(256) void colchunk_sum_k(
    const int* __restrict__ blockhist, int* __restrict__ chunksum,
    int nbk, int nblk, int nchk)
{
    int b = blockIdx.x * 256 + threadIdx.x;
    int c = blockIdx.y;
    if (b >= nbk) return;
    int k0 = c * CHK;
    int k1 = min(k0 + CHK, nblk);
    int s = 0;
    for (int k = k0; k < k1; k++) s += blockhist[(size_t)k * nbk + b];
    chunksum[(size_t)b * nchk + c] = s;
}

__global__ __launch_bounds__(256) void chunk_scan_k(
    int* __restrict__ chunksum, int* __restrict__ btot, int nbk, int nchk)
{
    int b = blockIdx.x * 256 + threadIdx.x;
    if (b >= nbk) return;
    int run = 0;
    int* row = chunksum + (size_t)b * nchk;
    for (int c = 0; c < nchk; c++) {
        int v = row[c];
        row[c] = run;
        run += v;
    }
    btot[b] = run;
}

__global__ __launch_bounds__(256) void scan_k(
    const int* __restrict__ btot, int* __restrict__ bbase,
    int* __restrict__ bucket_start, int* __restrict__ startv,
    int nbk, int n_nodes, int n_edges)
{
    __shared__ int ts[256];
    int t = threadIdx.x;
    int v[8];
    int s = 0;
#pragma unroll
    for (int j = 0; j < 8; j++) {
        int idx = t * 8 + j;
        v[j] = (idx < nbk) ? btot[idx] : 0;
        s += v[j];
    }
    ts[t] = s;
    __syncthreads();
    for (int off = 1; off < 256; off <<= 1) {
        int x = (t >= off) ? ts[t - off] : 0;
        __syncthreads();
        ts[t] += x;
        __syncthreads();
    }
    int run = ts[t] - s;
#pragma unroll
    for (int j = 0; j < 8; j++) {
        int idx = t * 8 + j;
        if (idx < nbk) { bbase[idx] = run; bucket_start[idx] = run; }
        run += v[j];
    }
    if (t == 255) { bucket_start[nbk] = n_edges; startv[n_nodes] = n_edges; }
}

__global__ __launch_bounds__(256) void col_off2_k(
    int* __restrict__ blockhist, const int* __restrict__ chunksum,
    const int* __restrict__ bbase, int nbk, int nblk, int nchk)
{
    int b = blockIdx.x * 256 + threadIdx.x;
    int c = blockIdx.y;
    if (b >= nbk) return;
    int k0 = c * CHK;
    int k1 = min(k0 + CHK, nblk);
    int run = bbase[b] + chunksum[(size_t)b * nchk + c];
    for (int k = k0; k < k1; k++) {
        size_t idx = (size_t)k * nbk + b;
        int v = blockhist[idx];
        blockhist[idx] = run;
        run += v;
    }
}

__global__ __launch_bounds__(256) void bin_scatter_k(
    const int* __restrict__ src, const int* __restrict__ dst,
    const int* __restrict__ blockhist, int* __restrict__ packedv,
    int n_edges, int nbk)
{
    extern __shared__ int cur[];
    const int* row = blockhist + (size_t)blockIdx.x * nbk;
    for (int i = threadIdx.x; i < nbk; i += 256) cur[i] = row[i];
    __syncthreads();
    int base = blockIdx.x * EPB;
    for (int i = threadIdx.x; i < EPB; i += 256) {
        int e = base + i;
        if (e < n_edges) {
            int d = dst[e];
            int pos = atomicAdd(&cur[d >> BSH], 1);
            packedv[pos] = ((d & 63) << 17) | src[e];
        }
    }
}

__global__ __launch_bounds__(256) void csr_k(
    const int* __restrict__ packedv, const int* __restrict__ bucket_start,
    int* __restrict__ nbr, int* __restrict__ startv, int n_nodes)
{
    __shared__ int hist[64];
    __shared__ int excl[64];
    __shared__ int cur[64];
    int b = blockIdx.x;
    int base = bucket_start[b];
    int end  = bucket_start[b + 1];
    if (threadIdx.x < 64) hist[threadIdx.x] = 0;
    __syncthreads();
    for (int i = base + threadIdx.x; i < end; i += 256)
        atomicAdd(&hist[packedv[i] >> 17], 1);
    __syncthreads();
    if (threadIdx.x == 0) {
        int r = 0;
        for (int k = 0; k < 64; k++) { excl[k] = r; r += hist[k]; }
    }
    __syncthreads();
    if (threadIdx.x < 64) {
        cur[threadIdx.x] = excl[threadIdx.x];
        int node = (b << 6) + threadIdx.x;
        if (node < n_nodes) startv[node] = base + excl[threadIdx.x];
    }
    __syncthreads();
    for (int i = base + threadIdx.x; i < end; i += 256) {
        int p = packedv[i];
        int pos = base + atomicAdd(&cur[p >> 17], 1);
        nbr[pos] = p & 0x1FFFF;
    }
}

// ---- batched gather core: 4 edges per lane per iteration (loads issued together) ----
// Converts the serial nbr->Brow 2-hop chain (~3 iterations/lane) into one batched
// round with 4 outstanding B-row loads. Invalid slots are masked via fma(mask,..).
__device__ __forceinline__ void gather_core(
    const float* __restrict__ A, const unsigned int* __restrict__ Bt,
    const f32x2 (&w1p)[10][5], const int* __restrict__ startv,
    const int* __restrict__ nbr, int n, int q, float (&hv)[10])
{
    const float4* ar = reinterpret_cast<const float4*>(A + (size_t)n * RS);
    float4 a0 = ar[0], a1 = ar[1], a2 = ar[2];
    f32x2 av2[5] = { {a0.x,a0.y}, {a0.z,a0.w}, {a1.x,a1.y}, {a1.z,a1.w}, {a2.x,a2.y} };

    f32x2 acc2[5];
#pragma unroll
    for (int h2 = 0; h2 < 5; h2++) acc2[h2] = (f32x2){0.f, 0.f};

    int beg = startv[n];
    int end = startv[n + 1];
    for (int i = beg + q; i < end; i += 16) {
        // ---- batch: clamp indices, issue all 4 nbr loads, then all 4 row loads ----
        int idx[4];
        float msk[4];
#pragma unroll
        for (int j = 0; j < 4; j++) {
            int ij = i + 4 * j;
            msk[j] = (ij < end) ? 1.f : 0.f;
            idx[j] = (ij < end) ? ij : i;
        }
        int s0 = nbr[idx[0]];
        int s1 = nbr[idx[1]];
        int s2 = nbr[idx[2]];
        int s3 = nbr[idx[3]];
        uint4 d[4];
        d[0] = *reinterpret_cast<const uint4*>(Bt + (size_t)s0 * BRS);
        d[1] = *reinterpret_cast<const uint4*>(Bt + (size_t)s1 * BRS);
        d[2] = *reinterpret_cast<const uint4*>(Bt + (size_t)s2 * BRS);
        d[3] = *reinterpret_cast<const uint4*>(Bt + (size_t)s3 * BRS);

#pragma unroll
        for (int j = 0; j < 4; j++) {
            unsigned int f0 = d[j].x & 0xFFFu;
            unsigned int f1 = (d[j].x >> 12) & 0xFFFu;
            unsigned int f2 = (d[j].x >> 24) | ((d[j].y & 0xFu) << 8);
            unsigned int f3 = (d[j].y >> 4) & 0xFFFu;
            unsigned int f4 = (d[j].y >> 16) & 0xFFFu;
            unsigned int f5 = ((d[j].y >> 28) & 0xFu) | ((d[j].z & 0xFFu) << 4);
            unsigned int f6 = (d[j].z >> 8) & 0xFFFu;
            unsigned int f7 = d[j].z >> 20;
            unsigned int f8 = d[j].w & 0xFFFu;
            unsigned int f9 = (d[j].w >> 12) & 0xFFFu;

            f32x2 pre[5];
            pre[0] = av2[0] + (f32x2){ fp12f(f0), fp12f(f1) };
            pre[1] = av2[1] + (f32x2){ fp12f(f2), fp12f(f3) };
            pre[2] = av2[2] + (f32x2){ fp12f(f4), fp12f(f5) };
            pre[3] = av2[3] + (f32x2){ fp12f(f6), fp12f(f7) };
            pre[4] = av2[4] + (f32x2){ fp12f(f8), fp12f(f9) };
#pragma unroll
            for (int k = 0; k < 5; k++) pre[k] = pk_max0(pre[k]);

            f32x2 z[5];
#pragma unroll
            for (int h2 = 0; h2 < 5; h2++) z[h2] = (f32x2){0.f, 0.f};
#pragma unroll
            for (int j2 = 0; j2 < 5; j2++) {
                f32x2 pa = (f32x2){ pre[j2].x, pre[j2].x };
                f32x2 pb = (f32x2){ pre[j2].y, pre[j2].y };
#pragma unroll
                for (int h2 = 0; h2 < 5; h2++) {
                    z[h2] = pk_fma(pa, w1p[2 * j2][h2], z[h2]);
                    z[h2] = pk_fma(pb, w1p[2 * j2 + 1][h2], z[h2]);
                }
            }
            f32x2 m2 = (f32x2){ msk[j], msk[j] };
#pragma unroll
            for (int h2 = 0; h2 < 5; h2++)
                acc2[h2] = pk_fma(m2, pk_max0(z[h2]), acc2[h2]);
        }
    }

#pragma unroll
    for (int h2 = 0; h2 < 5; h2++) {
        acc2[h2].x += __shfl_xor(acc2[h2].x, 1);
        acc2[h2].y += __shfl_xor(acc2[h2].y, 1);
    }
#pragma unroll
    for (int h2 = 0; h2 < 5; h2++) {
        acc2[h2].x += __shfl_xor(acc2[h2].x, 2);
        acc2[h2].y += __shfl_xor(acc2[h2].y, 2);
    }
#pragma unroll
    for (int h2 = 0; h2 < 5; h2++) {
        hv[2 * h2]     = acc2[h2].x * 0.1f;
        hv[2 * h2 + 1] = acc2[h2].y * 0.1f;
    }
}

// ---------- Middle gather layers: h -> next A (fp32) + next B (fp12), fused pre ----------
__global__ __launch_bounds__(256) void gather_mid_k(
    const float* __restrict__ A, const unsigned int* __restrict__ Bt,
    const float* __restrict__ W1, const float* __restrict__ W2n,
    const int* __restrict__ startv, const int* __restrict__ nbr,
    float* __restrict__ An, unsigned int* __restrict__ Bn, int n_nodes)
{
    __shared__ float w2s[200];
    for (int i = threadIdx.x; i < 200; i += 256) w2s[i] = W2n[i];
    __syncthreads();

    f32x2 w1p[10][5];
#pragma unroll
    for (int j = 0; j < 10; j++)
#pragma unroll
        for (int h2 = 0; h2 < 5; h2++)
            w1p[j][h2] = (f32x2){ W1[j * 10 + 2 * h2], W1[j * 10 + 2 * h2 + 1] };

    int t = blockIdx.x * 256 + threadIdx.x;
    int n = t >> 2;
    int q = t & 3;
    if (n >= n_nodes) return;

    float hv[10];
    gather_core(A, Bt, w1p, startv, nbr, n, q, hv);

    if (q == 0) {
        float a[8];
#pragma unroll
        for (int h = 0; h < 8; h++) {
            float zz = 0.f;
#pragma unroll
            for (int k = 0; k < 10; k++) zz = fmaf(hv[k], w2s[k * 10 + h], zz);
            a[h] = zz;
        }
        float4* Ar = reinterpret_cast<float4*>(An + (size_t)n * RS);
        Ar[0] = make_float4(a[0], a[1], a[2], a[3]);
        Ar[1] = make_float4(a[4], a[5], a[6], a[7]);
    } else if (q == 1) {
        float a8 = 0.f, a9 = 0.f;
#pragma unroll
        for (int k = 0; k < 10; k++) {
            a8 = fmaf(hv[k], w2s[k * 10 + 8], a8);
            a9 = fmaf(hv[k], w2s[k * 10 + 9], a9);
        }
        *reinterpret_cast<float2*>(An + (size_t)n * RS + 8) = make_float2(a8, a9);
    } else if (q == 2) {
        float bb[10];
#pragma unroll
        for (int h = 0; h < 10; h++) {
            float zz = 0.f;
#pragma unroll
            for (int k = 0; k < 10; k++) zz = fmaf(hv[k], w2s[100 + k * 10 + h], zz);
            bb[h] = zz;
        }
        *reinterpret_cast<uint4*>(Bn + (size_t)n * BRS) = pack10(bb);
    }
}

// ---------- Last gather layer FUSED with final MLP: out = relu(relu(h@Wf1)@Wf2) ----------
__global__ __launch_bounds__(256) void gather_fin_k(
    const float* __restrict__ A, const unsigned int* __restrict__ Bt,
    const float* __restrict__ W1,
    const int* __restrict__ startv, const int* __restrict__ nbr,
    const float* __restrict__ Wf1,  // [10,64]
    const float* __restrict__ Wf2,  // [64,64]
    float* __restrict__ out,        // [NN,64]
    int n_nodes)
{
    __shared__ float wf1[640];
    __shared__ float wf2s[4096];
    __shared__ float tT[4096];
    __shared__ float hvs[640];      // [64 nodes][10], stride 10

    for (int i = threadIdx.x; i < 640; i += 256) wf1[i] = Wf1[i];
    for (int i = threadIdx.x; i < 4096; i += 256) wf2s[i] = Wf2[i];

    f32x2 w1p[10][5];
#pragma unroll
    for (int j = 0; j < 10; j++)
#pragma unroll
        for (int h2 = 0; h2 < 5; h2++)
            w1p[j][h2] = (f32x2){ W1[j * 10 + 2 * h2], W1[j * 10 + 2 * h2 + 1] };

    int t0 = blockIdx.x * 256 + threadIdx.x;
    int n = t0 >> 2;
    int q = t0 & 3;
    int r = threadIdx.x >> 2;       // node index within block (0..63)

    float hv[10];
#pragma unroll
    for (int k = 0; k < 10; k++) hv[k] = 0.f;
    if (n < n_nodes)
        gather_core(A, Bt, w1p, startv, nbr, n, q, hv);

    if (q == 0) {
#pragma unroll
        for (int k = 0; k < 5; k++) hvs[r * 10 + k] = hv[k];
    } else if (q == 1) {
#pragma unroll
        for (int k = 5; k < 10; k++) hvs[r * 10 + k] = hv[k];
    }
    __syncthreads();

    // Stage 1: tT[c][r] = relu(hv[r] @ Wf1[:,c])
    {
        int rr = threadIdx.x & 63;
        int gg = threadIdx.x >> 6;
        float h[10];
#pragma unroll
        for (int k = 0; k < 10; k++) h[k] = hvs[rr * 10 + k];
#pragma unroll
        for (int j = 0; j < 16; j++) {
            int c = gg * 16 + j;
            float v = 0.f;
#pragma unroll
            for (int k = 0; k < 10; k++) v = fmaf(h[k], wf1[k * 64 + c], v);
            tT[c * 64 + rr] = fmaxf(v, 0.f);
        }
    }
    __syncthreads();

    // Stage 2: 4x4 register tile over [64 nodes x 64 cols]
    int node0 = blockIdx.x * 64;
    int r0 = (threadIdx.x >> 4) * 4;
    int c0 = (threadIdx.x & 15) * 4;
    float acc[4][4];
#pragma unroll
    for (int i = 0; i < 4; i++)
#pragma unroll
        for (int j = 0; j < 4; j++) acc[i][j] = 0.f;

    for (int k = 0; k < 64; k++) {
        float4 a = *reinterpret_cast<const float4*>(&tT[k * 64 + r0]);
        float4 b = *reinterpret_cast<const float4*>(&wf2s[k * 64 + c0]);
        float av[4] = { a.x, a.y, a.z, a.w };
        float bv[4] = { b.x, b.y, b.z, b.w };
#pragma unroll
        for (int i = 0; i < 4; i++)
#pragma unroll
            for (int j = 0; j < 4; j++)
                acc[i][j] = fmaf(av[i], bv[j], acc[i][j]);
    }

#pragma unroll
    for (int i = 0; i < 4; i++) {
        int node = node0 + r0 + i;
        if (node < n_nodes) {
            float4 o = make_float4(fmaxf(acc[i][0], 0.f), fmaxf(acc[i][1], 0.f),
                                   fmaxf(acc[i][2], 0.f), fmaxf(acc[i][3], 0.f));
            *reinterpret_cast<float4*>(&out[(size_t)node * FEAT + c0]) = o;
        }
    }
}

extern "C" void kernel_launch(void* const* d_in, const int* in_sizes, int n_in,
                              void* d_out, int out_size, void* d_ws, size_t ws_size,
                              hipStream_t stream) {
    const float* X    = (const float*)d_in[0];
    const float* W2_0 = (const float*)d_in[1];
    const float* W1_0 = (const float*)d_in[2];
    const float* W2_1 = (const float*)d_in[3];
    const float* W1_1 = (const float*)d_in[4];
    const float* W2_2 = (const float*)d_in[5];
    const float* W1_2 = (const float*)d_in[6];
    const float* Wf1  = (const float*)d_in[7];
    const float* Wf2  = (const float*)d_in[8];
    const int* src = (const int*)d_in[9];
    const int* dst = (const int*)d_in[10];
    float* out = (float*)d_out;

    const int n_edges = in_sizes[9];
    const int n_nodes = in_sizes[0] / FEAT;

    const int nbk  = (n_nodes + 63) >> 6;          // ~1563 buckets (<=2048 for scan_k)
    const int nblk = (n_edges + EPB - 1) / EPB;    // ~1221 binning blocks
    const int nchk = (nblk + CHK - 1) / CHK;       // ~39 column-prefix chunks

    const size_t h_elems = (size_t)n_nodes * RS;
    const size_t b_elems = (size_t)n_nodes * BRS;
    // ws layout (4B elems): A0 | A1 | B0 | B1 | nbr | packed | blockhist | chunksum | btot | bbase | bstart | startv
    const size_t offA0  = 0;
    const size_t offA1  = offA0 + h_elems;
    const size_t offB0  = offA1 + h_elems;
    const size_t offB1  = offB0 + b_elems;
    const size_t offNbr = offB1 + b_elems;
    const size_t offPk  = offNbr + (size_t)n_edges;
    const size_t offBh  = offPk + (size_t)n_edges;
    const size_t offCs  = offBh + (size_t)nblk * nbk;
    const size_t offBt  = offCs + (size_t)nbk * nchk;
    const size_t offBb  = offBt + (size_t)nbk;
    const size_t offBs  = offBb + (size_t)nbk;
    const size_t offSt  = offBs + (size_t)nbk + 1;

    float* A0           = (float*)d_ws + offA0;
    float* A1           = (float*)d_ws + offA1;
    unsigned int* B0    = (unsigned int*)d_ws + offB0;
    unsigned int* B1    = (unsigned int*)d_ws + offB1;
    int* nbr            = (int*)d_ws + offNbr;
    int* packedv        = (int*)d_ws + offPk;
    int* blockhist      = (int*)d_ws + offBh;
    int* chunksum       = (int*)d_ws + offCs;
    int* btot           = (int*)d_ws + offBt;
    int* bbase          = (int*)d_ws + offBb;
    int* bstart         = (int*)d_ws + offBs;
    int* startv         = (int*)d_ws + offSt;

    const int nb = (n_nodes + 255) / 256;
    const int gb = (n_nodes * 4 + 255) / 256;   // == ceil(n_nodes/64)
    const int cb = (nbk + 255) / 256;
    const size_t lds_bins = (size_t)nbk * 4;

    // ---- CSR build (LDS-cursor two-level counting sort) ----
    bin_hist_k<<<nblk, 256, lds_bins, stream>>>(dst, blockhist, n_edges, nbk);
    colchunk_sum_k<<<dim3(cb, nchk), 256, 0, stream>>>(blockhist, chunksum, nbk, nblk, nchk);
    chunk_scan_k<<<cb, 256, 0, stream>>>(chunksum, btot, nbk, nchk);
    scan_k<<<1, 256, 0, stream>>>(btot, bbase, bstart, startv, nbk, n_nodes, n_edges);
    col_off2_k<<<dim3(cb, nchk), 256, 0, stream>>>(blockhist, chunksum, bbase, nbk, nblk, nchk);
    bin_scatter_k<<<nblk, 256, lds_bins, stream>>>(src, dst, blockhist, packedv, n_edges, nbk);
    csr_k<<<nbk, 256, 0, stream>>>(packedv, bstart, nbr, startv, n_nodes);

    // ---- Layer 0 precompute + 2 mid gathers + fused last gather/final ----
    pre_l0<<<nb, 256, 0, stream>>>(X, W2_0, A0, B0, n_nodes);
    gather_mid_k<<<gb, 256, 0, stream>>>(A0, B0, W1_0, W2_1, startv, nbr, A1, B1, n_nodes);
    gather_mid_k<<<gb, 256, 0, stream>>>(A1, B1, W1_1, W2_2, startv, nbr, A0, B0, n_nodes);
    gather_fin_k<<<gb, 256, 0, stream>>>(A0, B0, W1_2, startv, nbr, Wf1, Wf2, out, n_nodes);
}

// Round 17
// 247.375 us; speedup vs baseline: 1.0336x; 1.0336x over previous
//
#include <hip/hip_runtime.h>
#include <hip/hip_fp16.h>

#define FEAT 64
#define HID 10
#define RS 16    // fp32 row stride (floats) -> 64B rows
#define BRS 4    // packed-fp12 B row stride (dwords) -> 16B rows
#define EPB 1024 // edges per block in binning passes -> ~1221 blocks
#define BSH 6    // bucket shift: 64 nodes per bucket
#define CHK 32   // block-rows per chunk in column-prefix passes

typedef __attribute__((ext_vector_type(2))) float f32x2;

#if defined(__has_builtin)
#if __has_builtin(__builtin_elementwise_fma)
#define HAVE_EW_FMA 1
#endif
#endif

__device__ __forceinline__ f32x2 pk_fma(f32x2 a, f32x2 b, f32x2 c) {
#ifdef HAVE_EW_FMA
    return __builtin_elementwise_fma(a, b, c);
#else
    f32x2 r; r.x = fmaf(a.x, b.x, c.x); r.y = fmaf(a.y, b.y, c.y); return r;
#endif
}
__device__ __forceinline__ f32x2 pk_max0(f32x2 a) {
    f32x2 r; r.x = fmaxf(a.x, 0.f); r.y = fmaxf(a.y, 0.f); return r;
}

// ---- fp12 (s1e5m6 = top 12 bits of fp16, RTN) codec ----
__device__ __forceinline__ unsigned int f2fp12(float v) {
    unsigned short h = __half_as_ushort(__float2half(v));
    return (((unsigned int)h) + 8u) >> 4;
}
__device__ __forceinline__ float fp12f(unsigned int f) {
    return __half2float(__ushort_as_half((unsigned short)(f << 4)));
}
__device__ __forceinline__ uint4 pack10(const float* b) {
    unsigned int f[10];
#pragma unroll
    for (int i = 0; i < 10; i++) f[i] = f2fp12(b[i]);
    uint4 d;
    d.x = f[0] | (f[1] << 12) | (f[2] << 24);
    d.y = (f[2] >> 8) | (f[3] << 4) | (f[4] << 16) | (f[5] << 28);
    d.z = (f[5] >> 4) | (f[6] << 8) | (f[7] << 20);
    d.w = f[8] | (f[9] << 12);
    return d;
}

// ---------- Layer-0 precompute: A=X@W2[0:64,:] (fp32), B=X@W2[64:128,:] (fp12 packed) ----------
__global__ __launch_bounds__(256) void pre_l0(
    const float* __restrict__ X,    // [NN,64]
    const float* __restrict__ W2,   // [128,10]
    float* __restrict__ A,          // [NN,RS] fp32
    unsigned int* __restrict__ Bt,  // [NN,BRS] packed fp12
    int n_nodes)
{
    __shared__ float w2[128 * 10];
    for (int i = threadIdx.x; i < 1280; i += 256) w2[i] = W2[i];
    __syncthreads();

    int n = blockIdx.x * 256 + threadIdx.x;
    if (n >= n_nodes) return;

    const float4* xr = reinterpret_cast<const float4*>(X + (size_t)n * FEAT);
    float a[10], b[10];
#pragma unroll
    for (int h = 0; h < 10; h++) { a[h] = 0.f; b[h] = 0.f; }

#pragma unroll
    for (int blk = 0; blk < 16; blk++) {
        float4 u = xr[blk];
        float xv[4] = { u.x, u.y, u.z, u.w };
#pragma unroll
        for (int j = 0; j < 4; j++) {
            int k = blk * 4 + j;
#pragma unroll
            for (int h = 0; h < 10; h++) {
                a[h] = fmaf(xv[j], w2[k * 10 + h], a[h]);
                b[h] = fmaf(xv[j], w2[(64 + k) * 10 + h], b[h]);
            }
        }
    }

    float4* Ar = reinterpret_cast<float4*>(A + (size_t)n * RS);
    Ar[0] = make_float4(a[0], a[1], a[2], a[3]);
    Ar[1] = make_float4(a[4], a[5], a[6], a[7]);
    Ar[2] = make_float4(a[8], a[9], 0.f, 0.f);
    *reinterpret_cast<uint4*>(Bt + (size_t)n * BRS) = pack10(b);
}

// ================= CSR build (R11-proven): two-level counting sort, LDS cursors only ==========

__global__ __launch_bounds__(256) void bin_hist_k(
    const int* __restrict__ dst, int* __restrict__ blockhist, int n_edges, int nbk)
{
    extern __shared__ int hist[];
    for (int i = threadIdx.x; i < nbk; i += 256) hist[i] = 0;
    __syncthreads();
    int base = blockIdx.x * EPB;
    for (int i = threadIdx.x; i < EPB; i += 256) {
        int e = base + i;
        if (e < n_edges) atomicAdd(&hist[dst[e] >> BSH], 1);
    }
    __syncthreads();
    int* row = blockhist + (size_t)blockIdx.x * nbk;
    for (int i = threadIdx.x; i < nbk; i += 256) row[i] = hist[i];
}

// chunksum is stored TRANSPOSED: chunksum[b * nchk + c]
__global__ __launch_bounds__(256) void colchunk_sum_k(
    const int* __restrict__ blockhist, int* __restrict__ chunksum,
    int nbk, int nblk, int nchk)
{
    int b = blockIdx.x * 256 + threadIdx.x;
    int c = blockIdx.y;
    if (b >= nbk) return;
    int k0 = c * CHK;
    int k1 = min(k0 + CHK, nblk);
    int s = 0;
    for (int k = k0; k < k1; k++) s += blockhist[(size_t)k * nbk + b];
    chunksum[(size_t)b * nchk + c] = s;
}

__global__ __launch_bounds__(256) void chunk_scan_k(
    int* __restrict__ chunksum, int* __restrict__ btot, int nbk, int nchk)
{
    int b = blockIdx.x * 256 + threadIdx.x;
    if (b >= nbk) return;
    int run = 0;
    int* row = chunksum + (size_t)b * nchk;
    for (int c = 0; c < nchk; c++) {
        int v = row[c];
        row[c] = run;
        run += v;
    }
    btot[b] = run;
}

__global__ __launch_bounds__(256) void scan_k(
    const int* __restrict__ btot, int* __restrict__ bbase,
    int* __restrict__ bucket_start, int* __restrict__ startv,
    int nbk, int n_nodes, int n_edges)
{
    __shared__ int ts[256];
    int t = threadIdx.x;
    int v[8];
    int s = 0;
#pragma unroll
    for (int j = 0; j < 8; j++) {
        int idx = t * 8 + j;
        v[j] = (idx < nbk) ? btot[idx] : 0;
        s += v[j];
    }
    ts[t] = s;
    __syncthreads();
    for (int off = 1; off < 256; off <<= 1) {
        int x = (t >= off) ? ts[t - off] : 0;
        __syncthreads();
        ts[t] += x;
        __syncthreads();
    }
    int run = ts[t] - s;
#pragma unroll
    for (int j = 0; j < 8; j++) {
        int idx = t * 8 + j;
        if (idx < nbk) { bbase[idx] = run; bucket_start[idx] = run; }
        run += v[j];
    }
    if (t == 255) { bucket_start[nbk] = n_edges; startv[n_nodes] = n_edges; }
}

__global__ __launch_bounds__(256) void col_off2_k(
    int* __restrict__ blockhist, const int* __restrict__ chunksum,
    const int* __restrict__ bbase, int nbk, int nblk, int nchk)
{
    int b = blockIdx.x * 256 + threadIdx.x;
    int c = blockIdx.y;
    if (b >= nbk) return;
    int k0 = c * CHK;
    int k1 = min(k0 + CHK, nblk);
    int run = bbase[b] + chunksum[(size_t)b * nchk + c];
    for (int k = k0; k < k1; k++) {
        size_t idx = (size_t)k * nbk + b;
        int v = blockhist[idx];
        blockhist[idx] = run;
        run += v;
    }
}

__global__ __launch_bounds__(256) void bin_scatter_k(
    const int* __restrict__ src, const int* __restrict__ dst,
    const int* __restrict__ blockhist, int* __restrict__ packedv,
    int n_edges, int nbk)
{
    extern __shared__ int cur[];
    const int* row = blockhist + (size_t)blockIdx.x * nbk;
    for (int i = threadIdx.x; i < nbk; i += 256) cur[i] = row[i];
    __syncthreads();
    int base = blockIdx.x * EPB;
    for (int i = threadIdx.x; i < EPB; i += 256) {
        int e = base + i;
        if (e < n_edges) {
            int d = dst[e];
            int pos = atomicAdd(&cur[d >> BSH], 1);
            packedv[pos] = ((d & 63) << 17) | src[e];
        }
    }
}

__global__ __launch_bounds__(256) void csr_k(
    const int* __restrict__ packedv, const int* __restrict__ bucket_start,
    int* __restrict__ nbr, int* __restrict__ startv, int n_nodes)
{
    __shared__ int hist[64];
    __shared__ int excl[64];
    __shared__ int cur[64];
    int b = blockIdx.x;
    int base = bucket_start[b];
    int end  = bucket_start[b + 1];
    if (threadIdx.x < 64) hist[threadIdx.x] = 0;
    __syncthreads();
    for (int i = base + threadIdx.x; i < end; i += 256)
        atomicAdd(&hist[packedv[i] >> 17], 1);
    __syncthreads();
    if (threadIdx.x == 0) {
        int r = 0;
        for (int k = 0; k < 64; k++) { excl[k] = r; r += hist[k]; }
    }
    __syncthreads();
    if (threadIdx.x < 64) {
        cur[threadIdx.x] = excl[threadIdx.x];
        int node = (b << 6) + threadIdx.x;
        if (node < n_nodes) startv[node] = base + excl[threadIdx.x];
    }
    __syncthreads();
    for (int i = base + threadIdx.x; i < end; i += 256) {
        int p = packedv[i];
        int pos = base + atomicAdd(&cur[p >> 17], 1);
        nbr[pos] = p & 0x1FFFF;
    }
}

// ---- decode + message helper (shared by both cores) ----
__device__ __forceinline__ void edge_msg(
    uint4 d, const f32x2 (&av2)[5], const f32x2 (&w1p)[10][5], f32x2 (&z)[5])
{
    unsigned int f0 = d.x & 0xFFFu;
    unsigned int f1 = (d.x >> 12) & 0xFFFu;
    unsigned int f2 = (d.x >> 24) | ((d.y & 0xFu) << 8);
    unsigned int f3 = (d.y >> 4) & 0xFFFu;
    unsigned int f4 = (d.y >> 16) & 0xFFFu;
    unsigned int f5 = ((d.y >> 28) & 0xFu) | ((d.z & 0xFFu) << 4);
    unsigned int f6 = (d.z >> 8) & 0xFFFu;
    unsigned int f7 = d.z >> 20;
    unsigned int f8 = d.w & 0xFFFu;
    unsigned int f9 = (d.w >> 12) & 0xFFFu;

    f32x2 pre[5];
    pre[0] = av2[0] + (f32x2){ fp12f(f0), fp12f(f1) };
    pre[1] = av2[1] + (f32x2){ fp12f(f2), fp12f(f3) };
    pre[2] = av2[2] + (f32x2){ fp12f(f4), fp12f(f5) };
    pre[3] = av2[3] + (f32x2){ fp12f(f6), fp12f(f7) };
    pre[4] = av2[4] + (f32x2){ fp12f(f8), fp12f(f9) };
#pragma unroll
    for (int k = 0; k < 5; k++) pre[k] = pk_max0(pre[k]);

#pragma unroll
    for (int h2 = 0; h2 < 5; h2++) z[h2] = (f32x2){0.f, 0.f};
#pragma unroll
    for (int j2 = 0; j2 < 5; j2++) {
        f32x2 pa = (f32x2){ pre[j2].x, pre[j2].x };
        f32x2 pb = (f32x2){ pre[j2].y, pre[j2].y };
#pragma unroll
        for (int h2 = 0; h2 < 5; h2++) {
            z[h2] = pk_fma(pa, w1p[2 * j2][h2], z[h2]);
            z[h2] = pk_fma(pb, w1p[2 * j2 + 1][h2], z[h2]);
        }
    }
}

// ---- SERIAL gather core (R15): best for mids (no trailing barrier; TLP hides latency) ----
__device__ __forceinline__ void gather_core_serial(
    const float* __restrict__ A, const unsigned int* __restrict__ Bt,
    const f32x2 (&w1p)[10][5], const int* __restrict__ startv,
    const int* __restrict__ nbr, int n, int q, float (&hv)[10])
{
    const float4* ar = reinterpret_cast<const float4*>(A + (size_t)n * RS);
    float4 a0 = ar[0], a1 = ar[1], a2 = ar[2];
    f32x2 av2[5] = { {a0.x,a0.y}, {a0.z,a0.w}, {a1.x,a1.y}, {a1.z,a1.w}, {a2.x,a2.y} };

    f32x2 acc2[5];
#pragma unroll
    for (int h2 = 0; h2 < 5; h2++) acc2[h2] = (f32x2){0.f, 0.f};

    int beg = startv[n];
    int end = startv[n + 1];
    for (int i = beg + q; i < end; i += 4) {
        int s = nbr[i];
        uint4 d = *reinterpret_cast<const uint4*>(Bt + (size_t)s * BRS);
        f32x2 z[5];
        edge_msg(d, av2, w1p, z);
#pragma unroll
        for (int h2 = 0; h2 < 5; h2++) acc2[h2] += pk_max0(z[h2]);
    }

#pragma unroll
    for (int h2 = 0; h2 < 5; h2++) {
        acc2[h2].x += __shfl_xor(acc2[h2].x, 1);
        acc2[h2].y += __shfl_xor(acc2[h2].y, 1);
    }
#pragma unroll
    for (int h2 = 0; h2 < 5; h2++) {
        acc2[h2].x += __shfl_xor(acc2[h2].x, 2);
        acc2[h2].y += __shfl_xor(acc2[h2].y, 2);
    }
#pragma unroll
    for (int h2 = 0; h2 < 5; h2++) {
        hv[2 * h2]     = acc2[h2].x * 0.1f;
        hv[2 * h2 + 1] = acc2[h2].y * 0.1f;
    }
}

// ---- BATCHED gather core (R16): best for fin (trailing barrier -> straggler-bound) ----
__device__ __forceinline__ void gather_core_batch(
    const float* __restrict__ A, const unsigned int* __restrict__ Bt,
    const f32x2 (&w1p)[10][5], const int* __restrict__ startv,
    const int* __restrict__ nbr, int n, int q, float (&hv)[10])
{
    const float4* ar = reinterpret_cast<const float4*>(A + (size_t)n * RS);
    float4 a0 = ar[0], a1 = ar[1], a2 = ar[2];
    f32x2 av2[5] = { {a0.x,a0.y}, {a0.z,a0.w}, {a1.x,a1.y}, {a1.z,a1.w}, {a2.x,a2.y} };

    f32x2 acc2[5];
#pragma unroll
    for (int h2 = 0; h2 < 5; h2++) acc2[h2] = (f32x2){0.f, 0.f};

    int beg = startv[n];
    int end = startv[n + 1];
    for (int i = beg + q; i < end; i += 16) {
        int idx[4];
        float msk[4];
#pragma unroll
        for (int j = 0; j < 4; j++) {
            int ij = i + 4 * j;
            msk[j] = (ij < end) ? 1.f : 0.f;
            idx[j] = (ij < end) ? ij : i;
        }
        int s0 = nbr[idx[0]];
        int s1 = nbr[idx[1]];
        int s2 = nbr[idx[2]];
        int s3 = nbr[idx[3]];
        uint4 d[4];
        d[0] = *reinterpret_cast<const uint4*>(Bt + (size_t)s0 * BRS);
        d[1] = *reinterpret_cast<const uint4*>(Bt + (size_t)s1 * BRS);
        d[2] = *reinterpret_cast<const uint4*>(Bt + (size_t)s2 * BRS);
        d[3] = *reinterpret_cast<const uint4*>(Bt + (size_t)s3 * BRS);

#pragma unroll
        for (int j = 0; j < 4; j++) {
            f32x2 z[5];
            edge_msg(d[j], av2, w1p, z);
            f32x2 m2 = (f32x2){ msk[j], msk[j] };
#pragma unroll
            for (int h2 = 0; h2 < 5; h2++)
                acc2[h2] = pk_fma(m2, pk_max0(z[h2]), acc2[h2]);
        }
    }

#pragma unroll
    for (int h2 = 0; h2 < 5; h2++) {
        acc2[h2].x += __shfl_xor(acc2[h2].x, 1);
        acc2[h2].y += __shfl_xor(acc2[h2].y, 1);
    }
#pragma unroll
    for (int h2 = 0; h2 < 5; h2++) {
        acc2[h2].x += __shfl_xor(acc2[h2].x, 2);
        acc2[h2].y += __shfl_xor(acc2[h2].y, 2);
    }
#pragma unroll
    for (int h2 = 0; h2 < 5; h2++) {
        hv[2 * h2]     = acc2[h2].x * 0.1f;
        hv[2 * h2 + 1] = acc2[h2].y * 0.1f;
    }
}

// ---------- Middle gather layers: h -> next A (fp32) + next B (fp12), fused pre ----------
__global__ __launch_bounds__(256) void gather_mid_k(
    const float* __restrict__ A, const unsigned int* __restrict__ Bt,
    const float* __restrict__ W1, const float* __restrict__ W2n,
    const int* __restrict__ startv, const int* __restrict__ nbr,
    float* __restrict__ An, unsigned int* __restrict__ Bn, int n_nodes)
{
    __shared__ float w2s[200];
    for (int i = threadIdx.x; i < 200; i += 256) w2s[i] = W2n[i];
    __syncthreads();

    f32x2 w1p[10][5];
#pragma unroll
    for (int j = 0; j < 10; j++)
#pragma unroll
        for (int h2 = 0; h2 < 5; h2++)
            w1p[j][h2] = (f32x2){ W1[j * 10 + 2 * h2], W1[j * 10 + 2 * h2 + 1] };

    int t = blockIdx.x * 256 + threadIdx.x;
    int n = t >> 2;
    int q = t & 3;
    if (n >= n_nodes) return;

    float hv[10];
    gather_core_serial(A, Bt, w1p, startv, nbr, n, q, hv);

    if (q == 0) {
        float a[8];
#pragma unroll
        for (int h = 0; h < 8; h++) {
            float zz = 0.f;
#pragma unroll
            for (int k = 0; k < 10; k++) zz = fmaf(hv[k], w2s[k * 10 + h], zz);
            a[h] = zz;
        }
        float4* Ar = reinterpret_cast<float4*>(An + (size_t)n * RS);
        Ar[0] = make_float4(a[0], a[1], a[2], a[3]);
        Ar[1] = make_float4(a[4], a[5], a[6], a[7]);
    } else if (q == 1) {
        float a8 = 0.f, a9 = 0.f;
#pragma unroll
        for (int k = 0; k < 10; k++) {
            a8 = fmaf(hv[k], w2s[k * 10 + 8], a8);
            a9 = fmaf(hv[k], w2s[k * 10 + 9], a9);
        }
        *reinterpret_cast<float2*>(An + (size_t)n * RS + 8) = make_float2(a8, a9);
    } else if (q == 2) {
        float bb[10];
#pragma unroll
        for (int h = 0; h < 10; h++) {
            float zz = 0.f;
#pragma unroll
            for (int k = 0; k < 10; k++) zz = fmaf(hv[k], w2s[100 + k * 10 + h], zz);
            bb[h] = zz;
        }
        *reinterpret_cast<uint4*>(Bn + (size_t)n * BRS) = pack10(bb);
    }
}

// ---------- Last gather layer FUSED with final MLP: out = relu(relu(h@Wf1)@Wf2) ----------
__global__ __launch_bounds__(256) void gather_fin_k(
    const float* __restrict__ A, const unsigned int* __restrict__ Bt,
    const float* __restrict__ W1,
    const int* __restrict__ startv, const int* __restrict__ nbr,
    const float* __restrict__ Wf1,  // [10,64]
    const float* __restrict__ Wf2,  // [64,64]
    float* __restrict__ out,        // [NN,64]
    int n_nodes)
{
    __shared__ float wf1[640];
    __shared__ float wf2s[4096];
    __shared__ float tT[4096];
    __shared__ float hvs[640];      // [64 nodes][10], stride 10

    for (int i = threadIdx.x; i < 640; i += 256) wf1[i] = Wf1[i];
    for (int i = threadIdx.x; i < 4096; i += 256) wf2s[i] = Wf2[i];

    f32x2 w1p[10][5];
#pragma unroll
    for (int j = 0; j < 10; j++)
#pragma unroll
        for (int h2 = 0; h2 < 5; h2++)
            w1p[j][h2] = (f32x2){ W1[j * 10 + 2 * h2], W1[j * 10 + 2 * h2 + 1] };

    int t0 = blockIdx.x * 256 + threadIdx.x;
    int n = t0 >> 2;
    int q = t0 & 3;
    int r = threadIdx.x >> 2;       // node index within block (0..63)

    float hv[10];
#pragma unroll
    for (int k = 0; k < 10; k++) hv[k] = 0.f;
    if (n < n_nodes)
        gather_core_batch(A, Bt, w1p, startv, nbr, n, q, hv);

    if (q == 0) {
#pragma unroll
        for (int k = 0; k < 5; k++) hvs[r * 10 + k] = hv[k];
    } else if (q == 1) {
#pragma unroll
        for (int k = 5; k < 10; k++) hvs[r * 10 + k] = hv[k];
    }
    __syncthreads();

    // Stage 1: tT[c][r] = relu(hv[r] @ Wf1[:,c])
    {
        int rr = threadIdx.x & 63;
        int gg = threadIdx.x >> 6;
        float h[10];
#pragma unroll
        for (int k = 0; k < 10; k++) h[k] = hvs[rr * 10 + k];
#pragma unroll
        for (int j = 0; j < 16; j++) {
            int c = gg * 16 + j;
            float v = 0.f;
#pragma unroll
            for (int k = 0; k < 10; k++) v = fmaf(h[k], wf1[k * 64 + c], v);
            tT[c * 64 + rr] = fmaxf(v, 0.f);
        }
    }
    __syncthreads();

    // Stage 2: 4x4 register tile over [64 nodes x 64 cols]
    int node0 = blockIdx.x * 64;
    int r0 = (threadIdx.x >> 4) * 4;
    int c0 = (threadIdx.x & 15) * 4;
    float acc[4][4];
#pragma unroll
    for (int i = 0; i < 4; i++)
#pragma unroll
        for (int j = 0; j < 4; j++) acc[i][j] = 0.f;

    for (int k = 0; k < 64; k++) {
        float4 a = *reinterpret_cast<const float4*>(&tT[k * 64 + r0]);
        float4 b = *reinterpret_cast<const float4*>(&wf2s[k * 64 + c0]);
        float av[4] = { a.x, a.y, a.z, a.w };
        float bv[4] = { b.x, b.y, b.z, b.w };
#pragma unroll
        for (int i = 0; i < 4; i++)
#pragma unroll
            for (int j = 0; j < 4; j++)
                acc[i][j] = fmaf(av[i], bv[j], acc[i][j]);
    }

#pragma unroll
    for (int i = 0; i < 4; i++) {
        int node = node0 + r0 + i;
        if (node < n_nodes) {
            float4 o = make_float4(fmaxf(acc[i][0], 0.f), fmaxf(acc[i][1], 0.f),
                                   fmaxf(acc[i][2], 0.f), fmaxf(acc[i][3], 0.f));
            *reinterpret_cast<float4*>(&out[(size_t)node * FEAT + c0]) = o;
        }
    }
}

extern "C" void kernel_launch(void* const* d_in, const int* in_sizes, int n_in,
                              void* d_out, int out_size, void* d_ws, size_t ws_size,
                              hipStream_t stream) {
    const float* X    = (const float*)d_in[0];
    const float* W2_0 = (const float*)d_in[1];
    const float* W1_0 = (const float*)d_in[2];
    const float* W2_1 = (const float*)d_in[3];
    const float* W1_1 = (const float*)d_in[4];
    const float* W2_2 = (const float*)d_in[5];
    const float* W1_2 = (const float*)d_in[6];
    const float* Wf1  = (const float*)d_in[7];
    const float* Wf2  = (const float*)d_in[8];
    const int* src = (const int*)d_in[9];
    const int* dst = (const int*)d_in[10];
    float* out = (float*)d_out;

    const int n_edges = in_sizes[9];
    const int n_nodes = in_sizes[0] / FEAT;

    const int nbk  = (n_nodes + 63) >> 6;          // ~1563 buckets (<=2048 for scan_k)
    const int nblk = (n_edges + EPB - 1) / EPB;    // ~1221 binning blocks
    const int nchk = (nblk + CHK - 1) / CHK;       // ~39 column-prefix chunks

    const size_t h_elems = (size_t)n_nodes * RS;
    const size_t b_elems = (size_t)n_nodes * BRS;
    // ws layout (4B elems): A0 | A1 | B0 | B1 | nbr | packed | blockhist | chunksum | btot | bbase | bstart | startv
    const size_t offA0  = 0;
    const size_t offA1  = offA0 + h_elems;
    const size_t offB0  = offA1 + h_elems;
    const size_t offB1  = offB0 + b_elems;
    const size_t offNbr = offB1 + b_elems;
    const size_t offPk  = offNbr + (size_t)n_edges;
    const size_t offBh  = offPk + (size_t)n_edges;
    const size_t offCs  = offBh + (size_t)nblk * nbk;
    const size_t offBt  = offCs + (size_t)nbk * nchk;
    const size_t offBb  = offBt + (size_t)nbk;
    const size_t offBs  = offBb + (size_t)nbk;
    const size_t offSt  = offBs + (size_t)nbk + 1;

    float* A0           = (float*)d_ws + offA0;
    float* A1           = (float*)d_ws + offA1;
    unsigned int* B0    = (unsigned int*)d_ws + offB0;
    unsigned int* B1    = (unsigned int*)d_ws + offB1;
    int* nbr            = (int*)d_ws + offNbr;
    int* packedv        = (int*)d_ws + offPk;
    int* blockhist      = (int*)d_ws + offBh;
    int* chunksum       = (int*)d_ws + offCs;
    int* btot           = (int*)d_ws + offBt;
    int* bbase          = (int*)d_ws + offBb;
    int* bstart         = (int*)d_ws + offBs;
    int* startv         = (int*)d_ws + offSt;

    const int nb = (n_nodes + 255) / 256;
    const int gb = (n_nodes * 4 + 255) / 256;   // == ceil(n_nodes/64)
    const int cb = (nbk + 255) / 256;
    const size_t lds_bins = (size_t)nbk * 4;

    // ---- CSR build (LDS-cursor two-level counting sort) ----
    bin_hist_k<<<nblk, 256, lds_bins, stream>>>(dst, blockhist, n_edges, nbk);
    colchunk_sum_k<<<dim3(cb, nchk), 256, 0, stream>>>(blockhist, chunksum, nbk, nblk, nchk);
    chunk_scan_k<<<cb, 256, 0, stream>>>(chunksum, btot, nbk, nchk);
    scan_k<<<1, 256, 0, stream>>>(btot, bbase, bstart, startv, nbk, n_nodes, n_edges);
    col_off2_k<<<dim3(cb, nchk), 256, 0, stream>>>(blockhist, chunksum, bbase, nbk, nblk, nchk);
    bin_scatter_k<<<nblk, 256, lds_bins, stream>>>(src, dst, blockhist, packedv, n_edges, nbk);
    csr_k<<<nbk, 256, 0, stream>>>(packedv, bstart, nbr, startv, n_nodes);

    // ---- Layer 0 precompute + 2 mid gathers (serial core) + fused last gather/final (batched core) ----
    pre_l0<<<nb, 256, 0, stream>>>(X, W2_0, A0, B0, n_nodes);
    gather_mid_k<<<gb, 256, 0, stream>>>(A0, B0, W1_0, W2_1, startv, nbr, A1, B1, n_nodes);
    gather_mid_k<<<gb, 256, 0, stream>>>(A1, B1, W1_1, W2_2, startv, nbr, A0, B0, n_nodes);
    gather_fin_k<<<gb, 256, 0, stream>>>(A0, B0, W1_2, startv, nbr, Wf1, Wf2, out, n_nodes);
}

// Round 18
// 244.430 us; speedup vs baseline: 1.0461x; 1.0121x over previous
//
#include <hip/hip_runtime.h>
#include <hip/hip_fp16.h>

#define FEAT 64
#define HID 10
#define RS 16    // fp32 row stride (floats) -> 64B rows
#define BRS 4    // packed-fp12 B row stride (dwords) -> 16B rows
#define EPB 1024 // edges per block in binning passes -> ~1221 blocks
#define BSH 6    // bucket shift: 64 nodes per bucket
#define CHK 32   // block-rows per chunk in column-prefix passes

typedef __attribute__((ext_vector_type(2))) float f32x2;

#if defined(__has_builtin)
#if __has_builtin(__builtin_elementwise_fma)
#define HAVE_EW_FMA 1
#endif
#endif

__device__ __forceinline__ f32x2 pk_fma(f32x2 a, f32x2 b, f32x2 c) {
#ifdef HAVE_EW_FMA
    return __builtin_elementwise_fma(a, b, c);
#else
    f32x2 r; r.x = fmaf(a.x, b.x, c.x); r.y = fmaf(a.y, b.y, c.y); return r;
#endif
}
__device__ __forceinline__ f32x2 pk_max0(f32x2 a) {
    f32x2 r; r.x = fmaxf(a.x, 0.f); r.y = fmaxf(a.y, 0.f); return r;
}

// ---- fp12 (s1e5m6 = top 12 bits of fp16, RTN) codec ----
__device__ __forceinline__ unsigned int f2fp12(float v) {
    unsigned short h = __half_as_ushort(__float2half(v));
    return (((unsigned int)h) + 8u) >> 4;
}
__device__ __forceinline__ float fp12f(unsigned int f) {
    return __half2float(__ushort_as_half((unsigned short)(f << 4)));
}
__device__ __forceinline__ uint4 pack10(const float* b) {
    unsigned int f[10];
#pragma unroll
    for (int i = 0; i < 10; i++) f[i] = f2fp12(b[i]);
    uint4 d;
    d.x = f[0] | (f[1] << 12) | (f[2] << 24);
    d.y = (f[2] >> 8) | (f[3] << 4) | (f[4] << 16) | (f[5] << 28);
    d.z = (f[5] >> 4) | (f[6] << 8) | (f[7] << 20);
    d.w = f[8] | (f[9] << 12);
    return d;
}

// ---------- Layer-0 precompute: A=X@W2[0:64,:] (fp32), B=X@W2[64:128,:] (fp12 packed) ----------
__global__ __launch_bounds__(256) void pre_l0(
    const float* __restrict__ X,    // [NN,64]
    const float* __restrict__ W2,   // [128,10]
    float* __restrict__ A,          // [NN,RS] fp32
    unsigned int* __restrict__ Bt,  // [NN,BRS] packed fp12
    int n_nodes)
{
    __shared__ float w2[128 * 10];
    for (int i = threadIdx.x; i < 1280; i += 256) w2[i] = W2[i];
    __syncthreads();

    int n = blockIdx.x * 256 + threadIdx.x;
    if (n >= n_nodes) return;

    const float4* xr = reinterpret_cast<const float4*>(X + (size_t)n * FEAT);
    float a[10], b[10];
#pragma unroll
    for (int h = 0; h < 10; h++) { a[h] = 0.f; b[h] = 0.f; }

#pragma unroll
    for (int blk = 0; blk < 16; blk++) {
        float4 u = xr[blk];
        float xv[4] = { u.x, u.y, u.z, u.w };
#pragma unroll
        for (int j = 0; j < 4; j++) {
            int k = blk * 4 + j;
#pragma unroll
            for (int h = 0; h < 10; h++) {
                a[h] = fmaf(xv[j], w2[k * 10 + h], a[h]);
                b[h] = fmaf(xv[j], w2[(64 + k) * 10 + h], b[h]);
            }
        }
    }

    float4* Ar = reinterpret_cast<float4*>(A + (size_t)n * RS);
    Ar[0] = make_float4(a[0], a[1], a[2], a[3]);
    Ar[1] = make_float4(a[4], a[5], a[6], a[7]);
    Ar[2] = make_float4(a[8], a[9], 0.f, 0.f);
    *reinterpret_cast<uint4*>(Bt + (size_t)n * BRS) = pack10(b);
}

// ================= CSR build: two-level counting sort, LDS cursors only ==========

__global__ __launch_bounds__(256) void bin_hist_k(
    const int* __restrict__ dst, int* __restrict__ blockhist, int n_edges, int nbk)
{
    extern __shared__ int hist[];
    for (int i = threadIdx.x; i < nbk; i += 256) hist[i] = 0;
    __syncthreads();
    int base = blockIdx.x * EPB;
    for (int i = threadIdx.x; i < EPB; i += 256) {
        int e = base + i;
        if (e < n_edges) atomicAdd(&hist[dst[e] >> BSH], 1);
    }
    __syncthreads();
    int* row = blockhist + (size_t)blockIdx.x * nbk;
    for (int i = threadIdx.x; i < nbk; i += 256) row[i] = hist[i];
}

// chunksum is stored TRANSPOSED: chunksum[b * nchk + c]
__global__ __launch_bounds__(256) void colchunk_sum_k(
    const int* __restrict__ blockhist, int* __restrict__ chunksum,
    int nbk, int nblk, int nchk)
{
    int b = blockIdx.x * 256 + threadIdx.x;
    int c = blockIdx.y;
    if (b >= nbk) return;
    int k0 = c * CHK;
    int k1 = min(k0 + CHK, nblk);
    int s = 0;
    for (int k = k0; k < k1; k++) s += blockhist[(size_t)k * nbk + b];
    chunksum[(size_t)b * nchk + c] = s;
}

__global__ __launch_bounds__(256) void chunk_scan_k(
    int* __restrict__ chunksum, int* __restrict__ btot, int nbk, int nchk)
{
    int b = blockIdx.x * 256 + threadIdx.x;
    if (b >= nbk) return;
    int run = 0;
    int* row = chunksum + (size_t)b * nchk;
    for (int c = 0; c < nchk; c++) {
        int v = row[c];
        row[c] = run;
        run += v;
    }
    btot[b] = run;
}

__global__ __launch_bounds__(256) void scan_k(
    const int* __restrict__ btot, int* __restrict__ bbase,
    int* __restrict__ bucket_start, int* __restrict__ startv,
    int nbk, int n_nodes, int n_edges)
{
    __shared__ int ts[256];
    int t = threadIdx.x;
    int v[8];
    int s = 0;
#pragma unroll
    for (int j = 0; j < 8; j++) {
        int idx = t * 8 + j;
        v[j] = (idx < nbk) ? btot[idx] : 0;
        s += v[j];
    }
    ts[t] = s;
    __syncthreads();
    for (int off = 1; off < 256; off <<= 1) {
        int x = (t >= off) ? ts[t - off] : 0;
        __syncthreads();
        ts[t] += x;
        __syncthreads();
    }
    int run = ts[t] - s;
#pragma unroll
    for (int j = 0; j < 8; j++) {
        int idx = t * 8 + j;
        if (idx < nbk) { bbase[idx] = run; bucket_start[idx] = run; }
        run += v[j];
    }
    if (t == 255) { bucket_start[nbk] = n_edges; startv[n_nodes] = n_edges; }
}

__global__ __launch_bounds__(256) void col_off2_k(
    int* __restrict__ blockhist, const int* __restrict__ chunksum,
    const int* __restrict__ bbase, int nbk, int nblk, int nchk)
{
    int b = blockIdx.x * 256 + threadIdx.x;
    int c = blockIdx.y;
    if (b >= nbk) return;
    int k0 = c * CHK;
    int k1 = min(k0 + CHK, nblk);
    int run = bbase[b] + chunksum[(size_t)b * nchk + c];
    for (int k = k0; k < k1; k++) {
        size_t idx = (size_t)k * nbk + b;
        int v = blockhist[idx];
        blockhist[idx] = run;
        run += v;
    }
}

__global__ __launch_bounds__(256) void bin_scatter_k(
    const int* __restrict__ src, const int* __restrict__ dst,
    const int* __restrict__ blockhist, int* __restrict__ packedv,
    int n_edges, int nbk)
{
    extern __shared__ int cur[];
    const int* row = blockhist + (size_t)blockIdx.x * nbk;
    for (int i = threadIdx.x; i < nbk; i += 256) cur[i] = row[i];
    __syncthreads();
    int base = blockIdx.x * EPB;
    for (int i = threadIdx.x; i < EPB; i += 256) {
        int e = base + i;
        if (e < n_edges) {
            int d = dst[e];
            int pos = atomicAdd(&cur[d >> BSH], 1);
            packedv[pos] = ((d & 63) << 17) | src[e];
        }
    }
}

// Per-bucket exact CSR + within-bucket degree-rank permutation.
// perm[b*64+rank] = global node id, ranked by descending degree (ties by id).
// Wave straggler fix: gathers process nodes in rank order -> a wave's 16 nodes
// have near-equal degree -> max/mean iteration ratio drops ~1.8x -> ~1.2x.
__global__ __launch_bounds__(256) void csr_k(
    const int* __restrict__ packedv, const int* __restrict__ bucket_start,
    int* __restrict__ nbr, int* __restrict__ startv, int* __restrict__ perm,
    int n_nodes)
{
    __shared__ int hist[64];
    __shared__ int excl[64];
    __shared__ int cur[64];
    int b = blockIdx.x;
    int base = bucket_start[b];
    int end  = bucket_start[b + 1];
    if (threadIdx.x < 64) hist[threadIdx.x] = 0;
    __syncthreads();
    for (int i = base + threadIdx.x; i < end; i += 256)
        atomicAdd(&hist[packedv[i] >> 17], 1);
    __syncthreads();
    if (threadIdx.x == 0) {
        int r = 0;
        for (int k = 0; k < 64; k++) { excl[k] = r; r += hist[k]; }
    }
    __syncthreads();
    if (threadIdx.x < 64) {
        int t = threadIdx.x;
        cur[t] = excl[t];
        int node = (b << 6) + t;
        if (node < n_nodes) startv[node] = base + excl[t];
        // degree ranking (descending; ties by local id). 64x64 broadcast reads.
        int d = hist[t];
        int rank = 0;
        for (int j = 0; j < 64; j++) {
            int dj = hist[j];
            rank += (dj > d) || (dj == d && j < t);
        }
        perm[(b << 6) + rank] = node;
    }
    __syncthreads();
    for (int i = base + threadIdx.x; i < end; i += 256) {
        int p = packedv[i];
        int pos = base + atomicAdd(&cur[p >> 17], 1);
        nbr[pos] = p & 0x1FFFF;
    }
}

// ---- serial gather core (per-node arithmetic identical to R15/R17) ----
__device__ __forceinline__ void gather_core(
    const float* __restrict__ A, const unsigned int* __restrict__ Bt,
    const f32x2 (&w1p)[10][5], const int* __restrict__ startv,
    const int* __restrict__ nbr, int n, int q, float (&hv)[10])
{
    const float4* ar = reinterpret_cast<const float4*>(A + (size_t)n * RS);
    float4 a0 = ar[0], a1 = ar[1], a2 = ar[2];
    f32x2 av2[5] = { {a0.x,a0.y}, {a0.z,a0.w}, {a1.x,a1.y}, {a1.z,a1.w}, {a2.x,a2.y} };

    f32x2 acc2[5];
#pragma unroll
    for (int h2 = 0; h2 < 5; h2++) acc2[h2] = (f32x2){0.f, 0.f};

    int beg = startv[n];
    int end = startv[n + 1];
    for (int i = beg + q; i < end; i += 4) {
        int s = nbr[i];
        uint4 d = *reinterpret_cast<const uint4*>(Bt + (size_t)s * BRS);
        unsigned int f0 = d.x & 0xFFFu;
        unsigned int f1 = (d.x >> 12) & 0xFFFu;
        unsigned int f2 = (d.x >> 24) | ((d.y & 0xFu) << 8);
        unsigned int f3 = (d.y >> 4) & 0xFFFu;
        unsigned int f4 = (d.y >> 16) & 0xFFFu;
        unsigned int f5 = ((d.y >> 28) & 0xFu) | ((d.z & 0xFFu) << 4);
        unsigned int f6 = (d.z >> 8) & 0xFFFu;
        unsigned int f7 = d.z >> 20;
        unsigned int f8 = d.w & 0xFFFu;
        unsigned int f9 = (d.w >> 12) & 0xFFFu;

        f32x2 pre[5];
        pre[0] = av2[0] + (f32x2){ fp12f(f0), fp12f(f1) };
        pre[1] = av2[1] + (f32x2){ fp12f(f2), fp12f(f3) };
        pre[2] = av2[2] + (f32x2){ fp12f(f4), fp12f(f5) };
        pre[3] = av2[3] + (f32x2){ fp12f(f6), fp12f(f7) };
        pre[4] = av2[4] + (f32x2){ fp12f(f8), fp12f(f9) };
#pragma unroll
        for (int k = 0; k < 5; k++) pre[k] = pk_max0(pre[k]);

        f32x2 z[5];
#pragma unroll
        for (int h2 = 0; h2 < 5; h2++) z[h2] = (f32x2){0.f, 0.f};
#pragma unroll
        for (int j2 = 0; j2 < 5; j2++) {
            f32x2 pa = (f32x2){ pre[j2].x, pre[j2].x };
            f32x2 pb = (f32x2){ pre[j2].y, pre[j2].y };
#pragma unroll
            for (int h2 = 0; h2 < 5; h2++) {
                z[h2] = pk_fma(pa, w1p[2 * j2][h2], z[h2]);
                z[h2] = pk_fma(pb, w1p[2 * j2 + 1][h2], z[h2]);
            }
        }
#pragma unroll
        for (int h2 = 0; h2 < 5; h2++) acc2[h2] += pk_max0(z[h2]);
    }

#pragma unroll
    for (int h2 = 0; h2 < 5; h2++) {
        acc2[h2].x += __shfl_xor(acc2[h2].x, 1);
        acc2[h2].y += __shfl_xor(acc2[h2].y, 1);
    }
#pragma unroll
    for (int h2 = 0; h2 < 5; h2++) {
        acc2[h2].x += __shfl_xor(acc2[h2].x, 2);
        acc2[h2].y += __shfl_xor(acc2[h2].y, 2);
    }
#pragma unroll
    for (int h2 = 0; h2 < 5; h2++) {
        hv[2 * h2]     = acc2[h2].x * 0.1f;
        hv[2 * h2 + 1] = acc2[h2].y * 0.1f;
    }
}

// ---------- Middle gather layers (degree-ranked node order): fused next-layer pre ----------
__global__ __launch_bounds__(256) void gather_mid_k(
    const float* __restrict__ A, const unsigned int* __restrict__ Bt,
    const float* __restrict__ W1, const float* __restrict__ W2n,
    const int* __restrict__ startv, const int* __restrict__ nbr,
    const int* __restrict__ perm,
    float* __restrict__ An, unsigned int* __restrict__ Bn, int n_nodes)
{
    __shared__ float w2s[200];
    for (int i = threadIdx.x; i < 200; i += 256) w2s[i] = W2n[i];
    __syncthreads();

    f32x2 w1p[10][5];
#pragma unroll
    for (int j = 0; j < 10; j++)
#pragma unroll
        for (int h2 = 0; h2 < 5; h2++)
            w1p[j][h2] = (f32x2){ W1[j * 10 + 2 * h2], W1[j * 10 + 2 * h2 + 1] };

    int slot = blockIdx.x * 64 + (threadIdx.x >> 2);
    int q = threadIdx.x & 3;
    int n = perm[slot];                 // broadcast within quad
    if (n >= n_nodes) return;

    float hv[10];
    gather_core(A, Bt, w1p, startv, nbr, n, q, hv);

    if (q == 0) {
        float a[8];
#pragma unroll
        for (int h = 0; h < 8; h++) {
            float zz = 0.f;
#pragma unroll
            for (int k = 0; k < 10; k++) zz = fmaf(hv[k], w2s[k * 10 + h], zz);
            a[h] = zz;
        }
        float4* Ar = reinterpret_cast<float4*>(An + (size_t)n * RS);
        Ar[0] = make_float4(a[0], a[1], a[2], a[3]);
        Ar[1] = make_float4(a[4], a[5], a[6], a[7]);
    } else if (q == 1) {
        float a8 = 0.f, a9 = 0.f;
#pragma unroll
        for (int k = 0; k < 10; k++) {
            a8 = fmaf(hv[k], w2s[k * 10 + 8], a8);
            a9 = fmaf(hv[k], w2s[k * 10 + 9], a9);
        }
        *reinterpret_cast<float2*>(An + (size_t)n * RS + 8) = make_float2(a8, a9);
    } else if (q == 2) {
        float bb[10];
#pragma unroll
        for (int h = 0; h < 10; h++) {
            float zz = 0.f;
#pragma unroll
            for (int k = 0; k < 10; k++) zz = fmaf(hv[k], w2s[100 + k * 10 + h], zz);
            bb[h] = zz;
        }
        *reinterpret_cast<uint4*>(Bn + (size_t)n * BRS) = pack10(bb);
    }
}

// ---------- Last gather (degree-ranked) FUSED with final MLP ----------
__global__ __launch_bounds__(256) void gather_fin_k(
    const float* __restrict__ A, const unsigned int* __restrict__ Bt,
    const float* __restrict__ W1,
    const int* __restrict__ startv, const int* __restrict__ nbr,
    const int* __restrict__ perm,
    const float* __restrict__ Wf1,  // [10,64]
    const float* __restrict__ Wf2,  // [64,64]
    float* __restrict__ out,        // [NN,64]
    int n_nodes)
{
    __shared__ float wf1[640];
    __shared__ float wf2s[4096];
    __shared__ float tT[4096];
    __shared__ float hvs[640];      // [64 local nodes][10]

    for (int i = threadIdx.x; i < 640; i += 256) wf1[i] = Wf1[i];
    for (int i = threadIdx.x; i < 4096; i += 256) wf2s[i] = Wf2[i];

    f32x2 w1p[10][5];
#pragma unroll
    for (int j = 0; j < 10; j++)
#pragma unroll
        for (int h2 = 0; h2 < 5; h2++)
            w1p[j][h2] = (f32x2){ W1[j * 10 + 2 * h2], W1[j * 10 + 2 * h2 + 1] };

    int node0 = blockIdx.x * 64;
    int slot = node0 + (threadIdx.x >> 2);
    int q = threadIdx.x & 3;
    int n = perm[slot];             // within-bucket permutation: n in [node0, node0+64)
    int r = n - node0;              // local id in [0,64)

    float hv[10];
#pragma unroll
    for (int k = 0; k < 10; k++) hv[k] = 0.f;
    if (n < n_nodes)
        gather_core(A, Bt, w1p, startv, nbr, n, q, hv);

    if (q == 0) {
#pragma unroll
        for (int k = 0; k < 5; k++) hvs[r * 10 + k] = hv[k];
    } else if (q == 1) {
#pragma unroll
        for (int k = 5; k < 10; k++) hvs[r * 10 + k] = hv[k];
    }
    __syncthreads();

    // Stage 1: tT[c][rr] = relu(hv[rr] @ Wf1[:,c])
    {
        int rr = threadIdx.x & 63;
        int gg = threadIdx.x >> 6;
        float h[10];
#pragma unroll
        for (int k = 0; k < 10; k++) h[k] = hvs[rr * 10 + k];
#pragma unroll
        for (int j = 0; j < 16; j++) {
            int c = gg * 16 + j;
            float v = 0.f;
#pragma unroll
            for (int k = 0; k < 10; k++) v = fmaf(h[k], wf1[k * 64 + c], v);
            tT[c * 64 + rr] = fmaxf(v, 0.f);
        }
    }
    __syncthreads();

    // Stage 2: 4x4 register tile over [64 nodes x 64 cols]
    int r0 = (threadIdx.x >> 4) * 4;
    int c0 = (threadIdx.x & 15) * 4;
    float acc[4][4];
#pragma unroll
    for (int i = 0; i < 4; i++)
#pragma unroll
        for (int j = 0; j < 4; j++) acc[i][j] = 0.f;

    for (int k = 0; k < 64; k++) {
        float4 a = *reinterpret_cast<const float4*>(&tT[k * 64 + r0]);
        float4 b = *reinterpret_cast<const float4*>(&wf2s[k * 64 + c0]);
        float av[4] = { a.x, a.y, a.z, a.w };
        float bv[4] = { b.x, b.y, b.z, b.w };
#pragma unroll
        for (int i = 0; i < 4; i++)
#pragma unroll
            for (int j = 0; j < 4; j++)
                acc[i][j] = fmaf(av[i], bv[j], acc[i][j]);
    }

#pragma unroll
    for (int i = 0; i < 4; i++) {
        int node = node0 + r0 + i;
        if (node < n_nodes) {
            float4 o = make_float4(fmaxf(acc[i][0], 0.f), fmaxf(acc[i][1], 0.f),
                                   fmaxf(acc[i][2], 0.f), fmaxf(acc[i][3], 0.f));
            *reinterpret_cast<float4*>(&out[(size_t)node * FEAT + c0]) = o;
        }
    }
}

extern "C" void kernel_launch(void* const* d_in, const int* in_sizes, int n_in,
                              void* d_out, int out_size, void* d_ws, size_t ws_size,
                              hipStream_t stream) {
    const float* X    = (const float*)d_in[0];
    const float* W2_0 = (const float*)d_in[1];
    const float* W1_0 = (const float*)d_in[2];
    const float* W2_1 = (const float*)d_in[3];
    const float* W1_1 = (const float*)d_in[4];
    const float* W2_2 = (const float*)d_in[5];
    const float* W1_2 = (const float*)d_in[6];
    const float* Wf1  = (const float*)d_in[7];
    const float* Wf2  = (const float*)d_in[8];
    const int* src = (const int*)d_in[9];
    const int* dst = (const int*)d_in[10];
    float* out = (float*)d_out;

    const int n_edges = in_sizes[9];
    const int n_nodes = in_sizes[0] / FEAT;

    const int nbk  = (n_nodes + 63) >> 6;          // ~1563 buckets (<=2048 for scan_k)
    const int nblk = (n_edges + EPB - 1) / EPB;    // ~1221 binning blocks
    const int nchk = (nblk + CHK - 1) / CHK;       // ~39 column-prefix chunks
    const size_t NP = (size_t)nbk << 6;            // padded node count

    const size_t h_elems = (size_t)n_nodes * RS;
    const size_t b_elems = (size_t)n_nodes * BRS;
    // ws layout (4B elems): A0 | A1 | B0 | B1 | nbr | packed | blockhist | chunksum | btot | bbase | bstart | startv | perm
    const size_t offA0  = 0;
    const size_t offA1  = offA0 + h_elems;
    const size_t offB0  = offA1 + h_elems;
    const size_t offB1  = offB0 + b_elems;
    const size_t offNbr = offB1 + b_elems;
    const size_t offPk  = offNbr + (size_t)n_edges;
    const size_t offBh  = offPk + (size_t)n_edges;
    const size_t offCs  = offBh + (size_t)nblk * nbk;
    const size_t offBt  = offCs + (size_t)nbk * nchk;
    const size_t offBb  = offBt + (size_t)nbk;
    const size_t offBs  = offBb + (size_t)nbk;
    const size_t offSt  = offBs + (size_t)nbk + 1;
    const size_t offPm  = offSt + (size_t)n_nodes + 1;

    float* A0           = (float*)d_ws + offA0;
    float* A1           = (float*)d_ws + offA1;
    unsigned int* B0    = (unsigned int*)d_ws + offB0;
    unsigned int* B1    = (unsigned int*)d_ws + offB1;
    int* nbr            = (int*)d_ws + offNbr;
    int* packedv        = (int*)d_ws + offPk;
    int* blockhist      = (int*)d_ws + offBh;
    int* chunksum       = (int*)d_ws + offCs;
    int* btot           = (int*)d_ws + offBt;
    int* bbase          = (int*)d_ws + offBb;
    int* bstart         = (int*)d_ws + offBs;
    int* startv         = (int*)d_ws + offSt;
    int* perm           = (int*)d_ws + offPm;
    (void)NP;

    const int nb = (n_nodes + 255) / 256;
    const int gb = nbk;                         // one block per 64-node bucket
    const int cb = (nbk + 255) / 256;
    const size_t lds_bins = (size_t)nbk * 4;

    // ---- CSR build (LDS-cursor two-level counting sort; csr_k also emits degree-rank perm) ----
    bin_hist_k<<<nblk, 256, lds_bins, stream>>>(dst, blockhist, n_edges, nbk);
    colchunk_sum_k<<<dim3(cb, nchk), 256, 0, stream>>>(blockhist, chunksum, nbk, nblk, nchk);
    chunk_scan_k<<<cb, 256, 0, stream>>>(chunksum, btot, nbk, nchk);
    scan_k<<<1, 256, 0, stream>>>(btot, bbase, bstart, startv, nbk, n_nodes, n_edges);
    col_off2_k<<<dim3(cb, nchk), 256, 0, stream>>>(blockhist, chunksum, bbase, nbk, nblk, nchk);
    bin_scatter_k<<<nblk, 256, lds_bins, stream>>>(src, dst, blockhist, packedv, n_edges, nbk);
    csr_k<<<nbk, 256, 0, stream>>>(packedv, bstart, nbr, startv, perm, n_nodes);

    // ---- Layer 0 precompute + 2 mid gathers + fused last gather/final (degree-ranked) ----
    pre_l0<<<nb, 256, 0, stream>>>(X, W2_0, A0, B0, n_nodes);
    gather_mid_k<<<gb, 256, 0, stream>>>(A0, B0, W1_0, W2_1, startv, nbr, perm, A1, B1, n_nodes);
    gather_mid_k<<<gb, 256, 0, stream>>>(A1, B1, W1_1, W2_2, startv, nbr, perm, A0, B0, n_nodes);
    gather_fin_k<<<gb, 256, 0, stream>>>(A0, B0, W1_2, startv, nbr, perm, Wf1, Wf2, out, n_nodes);
}